// Round 15
// baseline (452.433 us; speedup 1.0000x reference)
//
#include <hip/hip_runtime.h>
#include <cmath>

typedef short  short8 __attribute__((ext_vector_type(8)));
typedef float  f32x4  __attribute__((ext_vector_type(4)));
typedef unsigned short us8 __attribute__((ext_vector_type(8)));
typedef unsigned short us4 __attribute__((ext_vector_type(4)));

constexpr int kHW = 65536;           // 256*256
constexpr int kP  = 262144;          // 4 * kHW total pixels

__device__ __forceinline__ unsigned short f2bf(float x) {
  unsigned u = __builtin_bit_cast(unsigned, x);
  u += 0x7fffu + ((u >> 16) & 1u);
  return (unsigned short)(u >> 16);
}
__device__ __forceinline__ float bf2f(unsigned short h) {
  unsigned u = ((unsigned)h) << 16;
  return __builtin_bit_cast(float, u);
}
__device__ __forceinline__ void split2(float v, unsigned short& h, unsigned short& l) {
  unsigned short hh = f2bf(v);
  h = hh;
  l = f2bf(v - bf2f(hh));
}
__device__ __forceinline__ void gload16(const void* g, void* l) {
  __builtin_amdgcn_global_load_lds(
      (const __attribute__((address_space(1))) void*)g,
      (__attribute__((address_space(3))) void*)l, 16, 0, 0);
}
#define CFENCE() asm volatile("" ::: "memory")
#define WAITVM3() asm volatile("s_waitcnt vmcnt(3)" ::: "memory")
#define WAITVM0() asm volatile("s_waitcnt vmcnt(0)" ::: "memory")
#define SBAR() __builtin_amdgcn_s_barrier()

// ---------------- bias table: bias_tab[h][i][j], h<6, i,j<64 ----------------
__global__ void bias_kernel(const float* __restrict__ w1, const float* __restrict__ b1,
                            const float* __restrict__ w2, const float* __restrict__ b2,
                            float* __restrict__ bias_tab) {
  int i = blockIdx.x;
  int j = threadIdx.x;
  float dy = (float)((i >> 3) - (j >> 3));
  float dx = (float)((i & 7) - (j & 7));
  float r0 = copysignf(log1pf(fabsf(dy)), dy);
  float r1 = copysignf(log1pf(fabsf(dx)), dx);
  float acc[6];
#pragma unroll
  for (int h = 0; h < 6; ++h) acc[h] = b2[h];
  for (int t = 0; t < 256; ++t) {
    float hv = fmaf(r0, w1[t], fmaf(r1, w1[256 + t], b1[t]));
    hv = fmaxf(hv, 0.f);
#pragma unroll
    for (int h = 0; h < 6; ++h) acc[h] = fmaf(hv, w2[t * 6 + h], acc[h]);
  }
#pragma unroll
  for (int h = 0; h < 6; ++h) bias_tab[h * 4096 + i * 64 + j] = acc[h];
}

// ---------------- weight prep ------------------------------------------------
__global__ void prep_weights(const float* __restrict__ qk_w, const float* __restrict__ v_w,
                             const float* __restrict__ c1w, const float* __restrict__ c2w,
                             const float* __restrict__ pjw,
                             unsigned short* __restrict__ Wqh, unsigned short* __restrict__ Wql,
                             unsigned short* __restrict__ W1h,
                             unsigned short* __restrict__ W2h,
                             unsigned short* __restrict__ Wph, unsigned short* __restrict__ Wpl) {
  int i = blockIdx.x * 256 + threadIdx.x;
  if (i < 27648) {
    float v = (i < 18432) ? qk_w[i] : v_w[i - 18432];
    split2(v, Wqh[i], Wql[i]);
  }
  if (i < 82944) {
    int dlt = i / 9216;
    int oc  = (i / 96) % 96;
    int ic  = i % 96;
    int src = (oc * 96 + ic) * 9 + dlt;
    W1h[i] = f2bf(c1w[src]);
    W2h[i] = f2bf(c2w[src]);
  }
  if (i < 9216) split2(pjw[i], Wph[i], Wpl[i]);
}

// ---------------- X: NCHW fp32 -> NHWC bf16 (hi only) -----------------------
__global__ __launch_bounds__(256) void split_x(const float* __restrict__ X,
                                               unsigned short* __restrict__ Xh) {
  __shared__ float tile[96][65];
  int t = threadIdx.x;
  size_t p0 = (size_t)blockIdx.x * 64;
  int b = (int)(p0 >> 16), pix = (int)(p0 & 65535);
  const float* xb = X + (size_t)b * 96 * kHW + pix;
#pragma unroll
  for (int i = 0; i < 24; ++i) {
    int ic = (t >> 6) + i * 4;
    tile[ic][t & 63] = xb[(size_t)ic * kHW + (t & 63)];
  }
  __syncthreads();
  int px = t >> 2;
  size_t outbase = (p0 + px) * 96;
#pragma unroll
  for (int cc = 0; cc < 3; ++cc) {
    int c = (t & 3) + cc * 4;
    us8 h8;
#pragma unroll
    for (int j = 0; j < 8; ++j) h8[j] = f2bf(tile[c * 8 + j][px]);
    *(us8*)(Xh + outbase + c * 8) = h8;
  }
}

// ---------------- merged QKV GEMM: X read once; Q,K,V all head-planar -------
__global__ __launch_bounds__(256, 2) void qkv_gemm(
    const unsigned short* __restrict__ Wqh, const unsigned short* __restrict__ Wql,
    const unsigned short* __restrict__ Xh,
    const float* __restrict__ qk_b, const float* __restrict__ v_b,
    unsigned short* __restrict__ Qp, unsigned short* __restrict__ Kp,
    unsigned short* __restrict__ Vp) {
  int t = threadIdx.x, wv = t >> 6, lane = t & 63;
  size_t px0 = (size_t)blockIdx.x * 256 + wv * 64;
  int col = lane & 15, g = lane >> 4;

  const char* bH = (const char*)Xh + ((px0 + col) * 96 + g * 8) * 2;
  short8 Bh[3][4];
#pragma unroll
  for (int ks = 0; ks < 3; ++ks)
#pragma unroll
    for (int nf = 0; nf < 4; ++nf)
      Bh[ks][nf] = *(const short8*)(bH + (size_t)(nf * 16 * 96 + ks * 32) * 2);

#pragma unroll 1
  for (int z = 0; z < 3; ++z) {
    f32x4 acc[6][4];
#pragma unroll
    for (int m = 0; m < 6; ++m)
#pragma unroll
      for (int n = 0; n < 4; ++n) acc[m][n] = (f32x4)0.f;
    const char* aH = (const char*)(Wqh + z * 9216) + (size_t)(col * 96 + g * 8) * 2;
    const char* aL = (const char*)(Wql + z * 9216) + (size_t)(col * 96 + g * 8) * 2;
#pragma unroll
    for (int ks = 0; ks < 3; ++ks) {
      short8 Ah[6], Al[6];
#pragma unroll
      for (int mf = 0; mf < 6; ++mf) {
        Ah[mf] = *(const short8*)(aH + (size_t)(mf * 16 * 96 + ks * 32) * 2);
        Al[mf] = *(const short8*)(aL + (size_t)(mf * 16 * 96 + ks * 32) * 2);
      }
#pragma unroll
      for (int mf = 0; mf < 6; ++mf)
#pragma unroll
        for (int nf = 0; nf < 4; ++nf) {
          acc[mf][nf] = __builtin_amdgcn_mfma_f32_16x16x32_bf16(Ah[mf], Bh[ks][nf], acc[mf][nf], 0, 0, 0);
          acc[mf][nf] = __builtin_amdgcn_mfma_f32_16x16x32_bf16(Al[mf], Bh[ks][nf], acc[mf][nf], 0, 0, 0);
        }
    }
    const float* bias = (z == 0) ? qk_b : (z == 1 ? qk_b + 96 : v_b);
    float scale = (z == 0) ? 0.25f : 1.f;
    unsigned short* dst = (z == 0) ? Qp : (z == 1 ? Kp : Vp);
#pragma unroll
    for (int mf = 0; mf < 6; ++mf) {
      int oc0 = mf * 16 + g * 4;
      f32x4 bv;
#pragma unroll
      for (int r = 0; r < 4; ++r) bv[r] = bias[oc0 + r];
#pragma unroll
      for (int nf = 0; nf < 4; ++nf) {
        size_t p = px0 + nf * 16 + col;
        f32x4 v = (acc[mf][nf] + bv) * scale;
        us4 o;
#pragma unroll
        for (int r = 0; r < 4; ++r) o[r] = f2bf(v[r]);
        *(us4*)(dst + ((size_t)mf * kP + p) * 16 + g * 4) = o;   // head-planar
      }
    }
  }
}

// ---------------- attention via MFMA (wave = one window-head) ---------------
__global__ __launch_bounds__(256) void attn_mfma(
    const unsigned short* __restrict__ Qp, const unsigned short* __restrict__ Kp,
    const unsigned short* __restrict__ Vp, const float* __restrict__ bias_tab,
    unsigned short* __restrict__ out) {
  __shared__ unsigned short PT[4][64 * 72];   // per-wave P[q][k] bf16; reused as O[q][d]
  __shared__ unsigned short VT[4][16 * 72];   // per-wave V^T[d][k] bf16
  __shared__ float rls[4][64];                // per-wave 1/sum per q

  int t = threadIdx.x;
  int wv = t >> 6, lane = t & 63;
  int l15 = lane & 15, g = lane >> 4;
  int h = blockIdx.y;
  int wid = blockIdx.x * 4 + wv;
  int b = wid >> 10, wy = (wid >> 5) & 31, wx = wid & 31;
  size_t p0 = ((size_t)b << 16) + (size_t)wy * 8 * 256 + (size_t)wx * 8;
  const float* bt = bias_tab + h * 4096;

  f32x4 acc[4][4];   // [kf][qf]  C-init = bias
#pragma unroll
  for (int kf = 0; kf < 4; ++kf)
#pragma unroll
    for (int qf = 0; qf < 4; ++qf)
      acc[kf][qf] = *(const f32x4*)(bt + (qf * 16 + l15) * 64 + kf * 16 + g * 4);

  short8 Af[4], Bf[4];
#pragma unroll
  for (int f = 0; f < 4; ++f) {
    int kk = f * 16 + l15;
    size_t pk = p0 + (size_t)(kk >> 3) * 256 + (kk & 7);
    if (g < 2) {
      Af[f] = *(const short8*)(Kp + ((size_t)h * kP + pk) * 16 + g * 8);
      Bf[f] = *(const short8*)(Qp + ((size_t)h * kP + pk) * 16 + g * 8);
    } else {
      Af[f] = (short8)0;
      Bf[f] = (short8)0;
    }
  }

  // stage V^T[d][k] (own window pixel's 16 channels, head-planar V)
  {
    size_t pv = p0 + (size_t)(lane >> 3) * 256 + (lane & 7);
    const unsigned short* vp = Vp + ((size_t)h * kP + pv) * 16;
    us8 v0 = *(const us8*)(vp), v1 = *(const us8*)(vp + 8);
    unsigned short* vt = VT[wv];
#pragma unroll
    for (int d = 0; d < 8; ++d) {
      vt[d * 72 + lane]       = v0[d];
      vt[(d + 8) * 72 + lane] = v1[d];
    }
  }

#pragma unroll
  for (int kf = 0; kf < 4; ++kf)
#pragma unroll
    for (int qf = 0; qf < 4; ++qf)
      acc[kf][qf] = __builtin_amdgcn_mfma_f32_16x16x32_bf16(Af[kf], Bf[qf], acc[kf][qf], 0, 0, 0);

#pragma unroll
  for (int qf = 0; qf < 4; ++qf) {
    float m = acc[0][qf][0];
#pragma unroll
    for (int kf = 0; kf < 4; ++kf)
#pragma unroll
      for (int r = 0; r < 4; ++r) m = fmaxf(m, acc[kf][qf][r]);
    m = fmaxf(m, __shfl_xor(m, 16));
    m = fmaxf(m, __shfl_xor(m, 32));
    float sum = 0.f;
#pragma unroll
    for (int kf = 0; kf < 4; ++kf)
#pragma unroll
      for (int r = 0; r < 4; ++r) {
        float pe = __expf(acc[kf][qf][r] - m);
        acc[kf][qf][r] = pe;
        sum += pe;
      }
    sum += __shfl_xor(sum, 16);
    sum += __shfl_xor(sum, 32);
    if (g == 0) rls[wv][qf * 16 + l15] = 1.f / sum;
  }

  unsigned short* pt = PT[wv];
#pragma unroll
  for (int qf = 0; qf < 4; ++qf)
#pragma unroll
    for (int kf = 0; kf < 4; ++kf) {
      us4 pb;
#pragma unroll
      for (int r = 0; r < 4; ++r) pb[r] = f2bf(acc[kf][qf][r]);
      *(us4*)&pt[(qf * 16 + l15) * 72 + kf * 16 + g * 4] = pb;
    }

  short8 Pa[4][2], Vb[2];
#pragma unroll
  for (int qf = 0; qf < 4; ++qf)
#pragma unroll
    for (int kc = 0; kc < 2; ++kc)
      Pa[qf][kc] = *(const short8*)&pt[(qf * 16 + l15) * 72 + kc * 32 + g * 8];
#pragma unroll
  for (int kc = 0; kc < 2; ++kc)
    Vb[kc] = *(const short8*)&VT[wv][l15 * 72 + kc * 32 + g * 8];
  f32x4 o[4];
#pragma unroll
  for (int qf = 0; qf < 4; ++qf) {
    o[qf] = (f32x4)0.f;
#pragma unroll
    for (int kc = 0; kc < 2; ++kc)
      o[qf] = __builtin_amdgcn_mfma_f32_16x16x32_bf16(Pa[qf][kc], Vb[kc], o[qf], 0, 0, 0);
  }

#pragma unroll
  for (int qf = 0; qf < 4; ++qf) {
    f32x4 rv = *(const f32x4*)&rls[wv][qf * 16 + g * 4];
#pragma unroll
    for (int r = 0; r < 4; ++r)
      pt[(qf * 16 + g * 4 + r) * 72 + l15] = f2bf(o[qf][r] * rv[r]);
  }
  {
    int q = lane;
    us8 o0 = *(const us8*)&pt[q * 72];
    us8 o1 = *(const us8*)&pt[q * 72 + 8];
    size_t pq = p0 + (size_t)(q >> 3) * 256 + (q & 7);
    unsigned short* op = out + ((size_t)h * kP + pq) * 16;
    *(us8*)(op)     = o0;
    *(us8*)(op + 8) = o1;
  }
}

// ---------------- conv: 2-output-row blocks, 4 LDS slots, shared B-frags ----
// Block = 64-px strip x 96 oc x rows (y0, y0+1).  Slots = input rows
// y0-1, y0, y0+1, y0+2 (each staged ONCE).  Input row r feeds output y0 at
// tap (r-y0+1) and y0+1 at tap (r-y0): B-frag read once -> both rows' MFMAs.
// Slot layout: 16B chunk L = ks*264 + gp*66 + pp at byte L*16 (linear dst);
// source pre-swizzle: chunk carries (pp, c8 = ks*4 + (gp^(pp&3))).
// Slot = 832 chunks = 13312 B (792 staged + pad; == 64x208 transpose buffer).
constexpr int kSlotB = 13312;

__device__ __forceinline__ void stage_row(const char* __restrict__ rowbase,
                                          char* slot, const int (&off)[4], int t) {
  int wvbase = t & 192;
#pragma unroll
  for (int i = 0; i < 3; ++i)
    gload16(rowbase + off[i], slot + (i * 256 + wvbase) * 16);
  if (t < 64)                                   // wave 0 only: chunks 768..831
    gload16(rowbase + off[3], slot + 768 * 16);
}

template <bool R0, bool R1>
__device__ __forceinline__ void conv_slot(
    const char* __restrict__ lds_s, const unsigned short* __restrict__ Wh,
    int tapY, int tapY1, int och, int xq, int col, int g,
    f32x4 (&aY)[3][2], f32x4 (&aY1)[3][2]) {
#pragma unroll
  for (int dx = 0; dx < 3; ++dx) {
    int ppb = xq * 32 + col + dx;
#pragma unroll
    for (int ks = 0; ks < 3; ++ks) {
      short8 Bf[2];
#pragma unroll
      for (int nf = 0; nf < 2; ++nf) {
        int pp = ppb + nf * 16;
        Bf[nf] = *(const short8*)(lds_s + ks * 4224 + ((g ^ (pp & 3)) * 1056) + pp * 16);
      }
      if (R0) {
        const char* ah = (const char*)Wh + ((size_t)(tapY + dx) * 9216 + och * 4608 + col * 96 + g * 8) * 2;
        short8 Ah[3];
#pragma unroll
        for (int mf = 0; mf < 3; ++mf)
          Ah[mf] = *(const short8*)(ah + (size_t)(mf * 16 * 96 + ks * 32) * 2);
#pragma unroll
        for (int mf = 0; mf < 3; ++mf)
#pragma unroll
          for (int nf = 0; nf < 2; ++nf)
            aY[mf][nf] = __builtin_amdgcn_mfma_f32_16x16x32_bf16(Ah[mf], Bf[nf], aY[mf][nf], 0, 0, 0);
      }
      if (R1) {
        const char* ah = (const char*)Wh + ((size_t)(tapY1 + dx) * 9216 + och * 4608 + col * 96 + g * 8) * 2;
        short8 Ah[3];
#pragma unroll
        for (int mf = 0; mf < 3; ++mf)
          Ah[mf] = *(const short8*)(ah + (size_t)(mf * 16 * 96 + ks * 32) * 2);
#pragma unroll
        for (int mf = 0; mf < 3; ++mf)
#pragma unroll
          for (int nf = 0; nf < 2; ++nf)
            aY1[mf][nf] = __builtin_amdgcn_mfma_f32_16x16x32_bf16(Ah[mf], Bf[nf], aY1[mf][nf], 0, 0, 0);
      }
    }
  }
}

template <int MODE>
__device__ __forceinline__ void conv_epilogue(
    f32x4 (&acc)[3][2], char* tb, const float* __restrict__ bias,
    const unsigned short* __restrict__ attn, unsigned short* __restrict__ O_,
    int y, int b, int x0, int och, int xq, int col, int g, int t) {
  size_t prow = (size_t)b * kHW + (size_t)y * 256;
#pragma unroll
  for (int mf = 0; mf < 3; ++mf) {
    int oc0 = och * 48 + mf * 16 + g * 4;
    f32x4 bv;
#pragma unroll
    for (int r = 0; r < 4; ++r) bv[r] = bias[oc0 + r];
#pragma unroll
    for (int nf = 0; nf < 2; ++nf) {
      int pp = xq * 32 + nf * 16 + col;
      f32x4 v = acc[mf][nf] + bv;
      if (MODE == 0) {
#pragma unroll
        for (int r = 0; r < 4; ++r) v[r] = fmaxf(v[r], 0.f);
      } else {
        size_t p = prow + x0 + pp;
        us4 a4 = *(const us4*)(attn + ((size_t)(och * 3 + mf) * kP + p) * 16 + g * 4);
#pragma unroll
        for (int r = 0; r < 4; ++r) v[r] += bf2f(a4[r]);
      }
      us4 o;
#pragma unroll
      for (int r = 0; r < 4; ++r) o[r] = f2bf(v[r]);
      *(us4*)(tb + pp * 208 + oc0 * 2) = o;
    }
  }
  __syncthreads();
  {
    int px = t >> 2, q = t & 3;
    const char* src = tb + px * 208 + q * 48;
    us8 o0 = *(const us8*)(src);
    us8 o1 = *(const us8*)(src + 16);
    us8 o2 = *(const us8*)(src + 32);
    unsigned short* dst = O_ + (prow + x0 + px) * 96 + q * 24;
    *(us8*)(dst)      = o0;
    *(us8*)(dst + 8)  = o1;
    *(us8*)(dst + 16) = o2;
  }
}

template <int MODE>
__global__ __launch_bounds__(256, 3) void conv_gl(
    const unsigned short* __restrict__ Wh,
    const unsigned short* __restrict__ B_, const float* __restrict__ bias,
    const unsigned short* __restrict__ attn, unsigned short* __restrict__ O_) {
  __shared__ char lds[4][kSlotB];
  int t = threadIdx.x, wv = t >> 6, lane = t & 63;
  int col = lane & 15, g = lane >> 4;
  int och = wv >> 1, xq = wv & 1;
  int bid = blockIdx.x;
  int g8 = (bid & 7) * 256 + (bid >> 3);   // XCD-chunked over 2048 blocks
  int xh = g8 & 3;
  int rp = g8 >> 2;                        // 0..511 row-pairs
  int b = rp >> 7, y0 = (rp & 127) * 2;
  int x0 = xh * 64;

  // per-thread pre-swizzled source offsets (bytes); i=3 used by wave0 only
  int off[4];
#pragma unroll
  for (int i = 0; i < 4; ++i) {
    int idx = (i < 3) ? (i * 256 + t) : (768 + t);
    if (idx > 791) idx = 791;              // pad chunks: harmless duplicates
    int ks = idx / 264;
    int rem = idx - ks * 264;
    int gp = rem / 66;
    int pp = rem - gp * 66;
    int c8 = ks * 4 + (gp ^ (pp & 3));
    int xx = x0 - 1 + pp;
    xx = xx < 0 ? 1 : (xx > 255 ? 254 : xx);
    if (MODE == 0)
      off[i] = (((c8 >> 1) * kP + xx) * 16 + (c8 & 1) * 8) * 2;   // head-planar
    else
      off[i] = (xx * 96 + c8 * 8) * 2;                            // row-major
  }

  const size_t rowBytes = (MODE == 0) ? (size_t)256 * 32 : (size_t)256 * 192;
  const char* Bbase = (const char*)B_ + (size_t)b * kHW * ((MODE == 0) ? 32 : 192);
  int rA = (y0 == 0) ? 1 : y0 - 1;
  int rD = (y0 + 2 > 255) ? 254 : y0 + 2;

  f32x4 aY[3][2], aY1[3][2];
#pragma unroll
  for (int m = 0; m < 3; ++m)
#pragma unroll
    for (int n = 0; n < 2; ++n) { aY[m][n] = (f32x4)0.f; aY1[m][n] = (f32x4)0.f; }

  // stage all 4 input rows (each slot: w0=4 loads, w1-3=3 loads)
  stage_row(Bbase + (size_t)rA * rowBytes,       lds[0], off, t); CFENCE();
  stage_row(Bbase + (size_t)y0 * rowBytes,       lds[1], off, t); CFENCE();
  stage_row(Bbase + (size_t)(y0 + 1) * rowBytes, lds[2], off, t); CFENCE();
  stage_row(Bbase + (size_t)rD * rowBytes,       lds[3], off, t);
  WAITVM3(); SBAR();                        // slots A,B,C complete (D in flight)

  conv_slot<true,  false>(lds[0], Wh, 0, 0, och, xq, col, g, aY, aY1);
  conv_slot<true,  true >(lds[1], Wh, 3, 0, och, xq, col, g, aY, aY1);
  conv_slot<true,  true >(lds[2], Wh, 6, 3, och, xq, col, g, aY, aY1);
  WAITVM0(); SBAR();                        // slot D complete; all done reading A
  conv_slot<false, true >(lds[3], Wh, 0, 6, och, xq, col, g, aY, aY1);

  // epilogues: transpose through slot A (free), coalesced 48B/thread stores
  conv_epilogue<MODE>(aY,  lds[0], bias, attn, O_, y0,     b, x0, och, xq, col, g, t);
  __syncthreads();                          // row-y store reads done before reuse
  conv_epilogue<MODE>(aY1, lds[0], bias, attn, O_, y0 + 1, b, x0, och, xq, col, g, t);
}

// ---------------- final projection -> d_out NCHW fp32 ------------------------
__global__ __launch_bounds__(256, 2) void proj_gemm(
    const unsigned short* __restrict__ Wph, const unsigned short* __restrict__ Wpl,
    const unsigned short* __restrict__ S_, const float* __restrict__ bias,
    float* __restrict__ out) {
  int t = threadIdx.x, wv = t >> 6, lane = t & 63;
  size_t px0 = (size_t)blockIdx.x * 256 + wv * 64;
  int col = lane & 15, g = lane >> 4;
  f32x4 acc[6][4];
#pragma unroll
  for (int m = 0; m < 6; ++m)
#pragma unroll
    for (int n = 0; n < 4; ++n) acc[m][n] = (f32x4)0.f;
  const char* aH = (const char*)Wph + (size_t)(col * 96 + g * 8) * 2;
  const char* aL = (const char*)Wpl + (size_t)(col * 96 + g * 8) * 2;
  const char* bH = (const char*)S_ + ((px0 + col) * 96 + g * 8) * 2;
#pragma unroll
  for (int ks = 0; ks < 3; ++ks) {
    short8 Ah[6], Al[6], Bf[4];
#pragma unroll
    for (int mf = 0; mf < 6; ++mf) {
      Ah[mf] = *(const short8*)(aH + (size_t)(mf * 16 * 96 + ks * 32) * 2);
      Al[mf] = *(const short8*)(aL + (size_t)(mf * 16 * 96 + ks * 32) * 2);
    }
#pragma unroll
    for (int nf = 0; nf < 4; ++nf)
      Bf[nf] = *(const short8*)(bH + (size_t)(nf * 16 * 96 + ks * 32) * 2);
#pragma unroll
    for (int mf = 0; mf < 6; ++mf)
#pragma unroll
      for (int nf = 0; nf < 4; ++nf) {
        acc[mf][nf] = __builtin_amdgcn_mfma_f32_16x16x32_bf16(Ah[mf], Bf[nf], acc[mf][nf], 0, 0, 0);
        acc[mf][nf] = __builtin_amdgcn_mfma_f32_16x16x32_bf16(Al[mf], Bf[nf], acc[mf][nf], 0, 0, 0);
      }
  }
#pragma unroll
  for (int mf = 0; mf < 6; ++mf) {
    int oc0 = mf * 16 + g * 4;
#pragma unroll
    for (int nf = 0; nf < 4; ++nf) {
      size_t p = px0 + nf * 16 + col;
      size_t bb = p >> 16, pix = p & 65535;
      f32x4 v = acc[mf][nf];
#pragma unroll
      for (int r = 0; r < 4; ++r)
        out[(bb * 96 + oc0 + r) * (size_t)kHW + pix] = v[r] + bias[oc0 + r];
    }
  }
}

extern "C" void kernel_launch(void* const* d_in, const int* in_sizes, int n_in,
                              void* d_out, int out_size, void* d_ws, size_t ws_size,
                              hipStream_t stream) {
  const float* X       = (const float*)d_in[0];
  const float* V_w     = (const float*)d_in[1];
  const float* V_b     = (const float*)d_in[2];
  const float* QK_w    = (const float*)d_in[3];
  const float* QK_b    = (const float*)d_in[4];
  const float* meta_w1 = (const float*)d_in[5];
  const float* meta_b1 = (const float*)d_in[6];
  const float* meta_w2 = (const float*)d_in[7];
  const float* meta_b2 = (const float*)d_in[8];
  const float* conv1_w = (const float*)d_in[9];
  const float* conv1_b = (const float*)d_in[10];
  const float* conv2_w = (const float*)d_in[11];
  const float* conv2_b = (const float*)d_in[12];
  const float* proj_w  = (const float*)d_in[13];
  const float* proj_b  = (const float*)d_in[14];
  float* out = (float*)d_out;

  char* w = (char*)d_ws;
  const size_t PLANE = (size_t)kP * 96 * 2;      // 50,331,648 B
  unsigned short* Xh = (unsigned short*)(w + 0 * PLANE);
  unsigned short* Qp = (unsigned short*)(w + 1 * PLANE);
  unsigned short* Kp = (unsigned short*)(w + 2 * PLANE);
  unsigned short* Vp = (unsigned short*)(w + 3 * PLANE);
  float* bias_tab    = (float*)(w + 4 * PLANE);
  unsigned short* Wqh = (unsigned short*)(w + 4 * PLANE + 98304);
  unsigned short* Wql = Wqh + 27648;
  unsigned short* W1h = Wql + 27648;
  unsigned short* W2h = W1h + 82944;
  unsigned short* Wph = W2h + 82944;
  unsigned short* Wpl = Wph + 9216;
  // stream-ordered aliases
  unsigned short* T1r = Xh;            // X dead after qkv_gemm (row-major [p][96])
  unsigned short* S2r = Qp;            // Q dead after attn
  unsigned short* attnB = (unsigned short*)out;  // d_out as bf16 head-planar scratch

  bias_kernel<<<dim3(64), dim3(64), 0, stream>>>(meta_w1, meta_b1, meta_w2, meta_b2, bias_tab);
  prep_weights<<<dim3(324), dim3(256), 0, stream>>>(QK_w, V_w, conv1_w, conv2_w, proj_w,
                                                    Wqh, Wql, W1h, W2h, Wph, Wpl);
  split_x<<<dim3(4096), dim3(256), 0, stream>>>(X, Xh);
  qkv_gemm<<<dim3(1024), dim3(256), 0, stream>>>(Wqh, Wql, Xh, QK_b, V_b, Qp, Kp, Vp);
  attn_mfma<<<dim3(1024, 6), dim3(256), 0, stream>>>(Qp, Kp, Vp, bias_tab, attnB);
  conv_gl<0><<<dim3(2048), dim3(256), 0, stream>>>(W1h, Vp, conv1_b, nullptr, T1r);
  conv_gl<1><<<dim3(2048), dim3(256), 0, stream>>>(W2h, T1r, conv2_b, attnB, S2r);
  proj_gemm<<<dim3(1024), dim3(256), 0, stream>>>(Wph, Wpl, S2r, proj_b, out);
}

// Round 16
// 390.049 us; speedup vs baseline: 1.1599x; 1.1599x over previous
//
#include <hip/hip_runtime.h>
#include <cmath>

typedef short  short8 __attribute__((ext_vector_type(8)));
typedef float  f32x4  __attribute__((ext_vector_type(4)));
typedef unsigned short us8 __attribute__((ext_vector_type(8)));
typedef unsigned short us4 __attribute__((ext_vector_type(4)));

constexpr int kHW = 65536;           // 256*256
constexpr int kP  = 262144;          // 4 * kHW total pixels

__device__ __forceinline__ unsigned short f2bf(float x) {
  unsigned u = __builtin_bit_cast(unsigned, x);
  u += 0x7fffu + ((u >> 16) & 1u);
  return (unsigned short)(u >> 16);
}
__device__ __forceinline__ float bf2f(unsigned short h) {
  unsigned u = ((unsigned)h) << 16;
  return __builtin_bit_cast(float, u);
}
__device__ __forceinline__ void split2(float v, unsigned short& h, unsigned short& l) {
  unsigned short hh = f2bf(v);
  h = hh;
  l = f2bf(v - bf2f(hh));
}

// ---------------- bias table: bias_tab[h][i][j], h<6, i,j<64 ----------------
__global__ void bias_kernel(const float* __restrict__ w1, const float* __restrict__ b1,
                            const float* __restrict__ w2, const float* __restrict__ b2,
                            float* __restrict__ bias_tab) {
  int i = blockIdx.x;
  int j = threadIdx.x;
  float dy = (float)((i >> 3) - (j >> 3));
  float dx = (float)((i & 7) - (j & 7));
  float r0 = copysignf(log1pf(fabsf(dy)), dy);
  float r1 = copysignf(log1pf(fabsf(dx)), dx);
  float acc[6];
#pragma unroll
  for (int h = 0; h < 6; ++h) acc[h] = b2[h];
  for (int t = 0; t < 256; ++t) {
    float hv = fmaf(r0, w1[t], fmaf(r1, w1[256 + t], b1[t]));
    hv = fmaxf(hv, 0.f);
#pragma unroll
    for (int h = 0; h < 6; ++h) acc[h] = fmaf(hv, w2[t * 6 + h], acc[h]);
  }
#pragma unroll
  for (int h = 0; h < 6; ++h) bias_tab[h * 4096 + i * 64 + j] = acc[h];
}

// ---------------- weight prep ------------------------------------------------
__global__ void prep_weights(const float* __restrict__ qk_w, const float* __restrict__ v_w,
                             const float* __restrict__ c1w, const float* __restrict__ c2w,
                             const float* __restrict__ pjw,
                             unsigned short* __restrict__ Wqh, unsigned short* __restrict__ Wql,
                             unsigned short* __restrict__ W1h,
                             unsigned short* __restrict__ W2h,
                             unsigned short* __restrict__ Wph, unsigned short* __restrict__ Wpl) {
  int i = blockIdx.x * 256 + threadIdx.x;
  if (i < 27648) {
    float v = (i < 18432) ? qk_w[i] : v_w[i - 18432];
    split2(v, Wqh[i], Wql[i]);
  }
  if (i < 82944) {
    int dlt = i / 9216;
    int oc  = (i / 96) % 96;
    int ic  = i % 96;
    int src = (oc * 96 + ic) * 9 + dlt;
    W1h[i] = f2bf(c1w[src]);
    W2h[i] = f2bf(c2w[src]);
  }
  if (i < 9216) split2(pjw[i], Wph[i], Wpl[i]);
}

// ---------------- X: NCHW fp32 -> NHWC bf16 (hi only) -----------------------
__global__ __launch_bounds__(256) void split_x(const float* __restrict__ X,
                                               unsigned short* __restrict__ Xh) {
  __shared__ float tile[96][65];
  int t = threadIdx.x;
  size_t p0 = (size_t)blockIdx.x * 64;
  int b = (int)(p0 >> 16), pix = (int)(p0 & 65535);
  const float* xb = X + (size_t)b * 96 * kHW + pix;
#pragma unroll
  for (int i = 0; i < 24; ++i) {
    int ic = (t >> 6) + i * 4;
    tile[ic][t & 63] = xb[(size_t)ic * kHW + (t & 63)];
  }
  __syncthreads();
  int px = t >> 2;
  size_t outbase = (p0 + px) * 96;
#pragma unroll
  for (int cc = 0; cc < 3; ++cc) {
    int c = (t & 3) + cc * 4;
    us8 h8;
#pragma unroll
    for (int j = 0; j < 8; ++j) h8[j] = f2bf(tile[c * 8 + j][px]);
    *(us8*)(Xh + outbase + c * 8) = h8;
  }
}

// ---------------- merged QKV GEMM: X read once; Q,K,V all c8-planar ---------
// c8-planar: element (channel-block c8, pixel p, ch r) at (c8*kP + p)*8 + r.
__global__ __launch_bounds__(256, 2) void qkv_gemm(
    const unsigned short* __restrict__ Wqh, const unsigned short* __restrict__ Wql,
    const unsigned short* __restrict__ Xh,
    const float* __restrict__ qk_b, const float* __restrict__ v_b,
    unsigned short* __restrict__ Qp, unsigned short* __restrict__ Kp,
    unsigned short* __restrict__ Vp) {
  int t = threadIdx.x, wv = t >> 6, lane = t & 63;
  size_t px0 = (size_t)blockIdx.x * 256 + wv * 64;
  int col = lane & 15, g = lane >> 4;

  const char* bH = (const char*)Xh + ((px0 + col) * 96 + g * 8) * 2;
  short8 Bh[3][4];
#pragma unroll
  for (int ks = 0; ks < 3; ++ks)
#pragma unroll
    for (int nf = 0; nf < 4; ++nf)
      Bh[ks][nf] = *(const short8*)(bH + (size_t)(nf * 16 * 96 + ks * 32) * 2);

#pragma unroll 1
  for (int z = 0; z < 3; ++z) {
    f32x4 acc[6][4];
#pragma unroll
    for (int m = 0; m < 6; ++m)
#pragma unroll
      for (int n = 0; n < 4; ++n) acc[m][n] = (f32x4)0.f;
    const char* aH = (const char*)(Wqh + z * 9216) + (size_t)(col * 96 + g * 8) * 2;
    const char* aL = (const char*)(Wql + z * 9216) + (size_t)(col * 96 + g * 8) * 2;
#pragma unroll
    for (int ks = 0; ks < 3; ++ks) {
      short8 Ah[6], Al[6];
#pragma unroll
      for (int mf = 0; mf < 6; ++mf) {
        Ah[mf] = *(const short8*)(aH + (size_t)(mf * 16 * 96 + ks * 32) * 2);
        Al[mf] = *(const short8*)(aL + (size_t)(mf * 16 * 96 + ks * 32) * 2);
      }
#pragma unroll
      for (int mf = 0; mf < 6; ++mf)
#pragma unroll
        for (int nf = 0; nf < 4; ++nf) {
          acc[mf][nf] = __builtin_amdgcn_mfma_f32_16x16x32_bf16(Ah[mf], Bh[ks][nf], acc[mf][nf], 0, 0, 0);
          acc[mf][nf] = __builtin_amdgcn_mfma_f32_16x16x32_bf16(Al[mf], Bh[ks][nf], acc[mf][nf], 0, 0, 0);
        }
    }
    const float* bias = (z == 0) ? qk_b : (z == 1 ? qk_b + 96 : v_b);
    float scale = (z == 0) ? 0.25f : 1.f;
    unsigned short* dst = (z == 0) ? Qp : (z == 1 ? Kp : Vp);
#pragma unroll
    for (int mf = 0; mf < 6; ++mf) {
      int oc0 = mf * 16 + g * 4;
      int c8 = mf * 2 + (g >> 1);
      f32x4 bv;
#pragma unroll
      for (int r = 0; r < 4; ++r) bv[r] = bias[oc0 + r];
#pragma unroll
      for (int nf = 0; nf < 4; ++nf) {
        size_t p = px0 + nf * 16 + col;
        f32x4 v = (acc[mf][nf] + bv) * scale;
        us4 o;
#pragma unroll
        for (int r = 0; r < 4; ++r) o[r] = f2bf(v[r]);
        *(us4*)(dst + ((size_t)c8 * kP + p) * 8 + (g & 1) * 4) = o;
      }
    }
  }
}

// ---------------- attention via MFMA (wave = one window-head) ---------------
__global__ __launch_bounds__(256) void attn_mfma(
    const unsigned short* __restrict__ Qp, const unsigned short* __restrict__ Kp,
    const unsigned short* __restrict__ Vp, const float* __restrict__ bias_tab,
    unsigned short* __restrict__ out) {
  __shared__ unsigned short PT[4][64 * 72];   // per-wave P[q][k] bf16; reused as O[q][d]
  __shared__ unsigned short VT[4][16 * 72];   // per-wave V^T[d][k] bf16
  __shared__ float rls[4][64];                // per-wave 1/sum per q

  int t = threadIdx.x;
  int wv = t >> 6, lane = t & 63;
  int l15 = lane & 15, g = lane >> 4;
  int h = blockIdx.y;
  int wid = blockIdx.x * 4 + wv;
  int b = wid >> 10, wy = (wid >> 5) & 31, wx = wid & 31;
  size_t p0 = ((size_t)b << 16) + (size_t)wy * 8 * 256 + (size_t)wx * 8;
  const float* bt = bias_tab + h * 4096;

  f32x4 acc[4][4];   // [kf][qf]  C-init = bias
#pragma unroll
  for (int kf = 0; kf < 4; ++kf)
#pragma unroll
    for (int qf = 0; qf < 4; ++qf)
      acc[kf][qf] = *(const f32x4*)(bt + (qf * 16 + l15) * 64 + kf * 16 + g * 4);

  short8 Af[4], Bf[4];
#pragma unroll
  for (int f = 0; f < 4; ++f) {
    int kk = f * 16 + l15;
    size_t pk = p0 + (size_t)(kk >> 3) * 256 + (kk & 7);
    if (g < 2) {
      size_t pl = (size_t)(2 * h + g) * kP;
      Af[f] = *(const short8*)(Kp + (pl + pk) * 8);
      Bf[f] = *(const short8*)(Qp + (pl + pk) * 8);
    } else {
      Af[f] = (short8)0;
      Bf[f] = (short8)0;
    }
  }

  // stage V^T[d][k] (own window pixel's 16 channels, c8-planar V)
  {
    size_t pv = p0 + (size_t)(lane >> 3) * 256 + (lane & 7);
    us8 v0 = *(const us8*)(Vp + ((size_t)(2 * h) * kP + pv) * 8);
    us8 v1 = *(const us8*)(Vp + ((size_t)(2 * h + 1) * kP + pv) * 8);
    unsigned short* vt = VT[wv];
#pragma unroll
    for (int d = 0; d < 8; ++d) {
      vt[d * 72 + lane]       = v0[d];
      vt[(d + 8) * 72 + lane] = v1[d];
    }
  }

#pragma unroll
  for (int kf = 0; kf < 4; ++kf)
#pragma unroll
    for (int qf = 0; qf < 4; ++qf)
      acc[kf][qf] = __builtin_amdgcn_mfma_f32_16x16x32_bf16(Af[kf], Bf[qf], acc[kf][qf], 0, 0, 0);

#pragma unroll
  for (int qf = 0; qf < 4; ++qf) {
    float m = acc[0][qf][0];
#pragma unroll
    for (int kf = 0; kf < 4; ++kf)
#pragma unroll
      for (int r = 0; r < 4; ++r) m = fmaxf(m, acc[kf][qf][r]);
    m = fmaxf(m, __shfl_xor(m, 16));
    m = fmaxf(m, __shfl_xor(m, 32));
    float sum = 0.f;
#pragma unroll
    for (int kf = 0; kf < 4; ++kf)
#pragma unroll
      for (int r = 0; r < 4; ++r) {
        float pe = __expf(acc[kf][qf][r] - m);
        acc[kf][qf][r] = pe;
        sum += pe;
      }
    sum += __shfl_xor(sum, 16);
    sum += __shfl_xor(sum, 32);
    if (g == 0) rls[wv][qf * 16 + l15] = 1.f / sum;
  }

  unsigned short* pt = PT[wv];
#pragma unroll
  for (int qf = 0; qf < 4; ++qf)
#pragma unroll
    for (int kf = 0; kf < 4; ++kf) {
      us4 pb;
#pragma unroll
      for (int r = 0; r < 4; ++r) pb[r] = f2bf(acc[kf][qf][r]);
      *(us4*)&pt[(qf * 16 + l15) * 72 + kf * 16 + g * 4] = pb;
    }

  short8 Pa[4][2], Vb[2];
#pragma unroll
  for (int qf = 0; qf < 4; ++qf)
#pragma unroll
    for (int kc = 0; kc < 2; ++kc)
      Pa[qf][kc] = *(const short8*)&pt[(qf * 16 + l15) * 72 + kc * 32 + g * 8];
#pragma unroll
  for (int kc = 0; kc < 2; ++kc)
    Vb[kc] = *(const short8*)&VT[wv][l15 * 72 + kc * 32 + g * 8];
  f32x4 o[4];
#pragma unroll
  for (int qf = 0; qf < 4; ++qf) {
    o[qf] = (f32x4)0.f;
#pragma unroll
    for (int kc = 0; kc < 2; ++kc)
      o[qf] = __builtin_amdgcn_mfma_f32_16x16x32_bf16(Pa[qf][kc], Vb[kc], o[qf], 0, 0, 0);
  }

#pragma unroll
  for (int qf = 0; qf < 4; ++qf) {
    f32x4 rv = *(const f32x4*)&rls[wv][qf * 16 + g * 4];
#pragma unroll
    for (int r = 0; r < 4; ++r)
      pt[(qf * 16 + g * 4 + r) * 72 + l15] = f2bf(o[qf][r] * rv[r]);
  }
  {
    int q = lane;
    us8 o0 = *(const us8*)&pt[q * 72];
    us8 o1 = *(const us8*)&pt[q * 72 + 8];
    size_t pq = p0 + (size_t)(q >> 3) * 256 + (q & 7);
    *(us8*)(out + ((size_t)(2 * h) * kP + pq) * 8)     = o0;
    *(us8*)(out + ((size_t)(2 * h + 1) * kP + pq) * 8) = o1;
  }
}

// ---------------- conv: zero-LDS, direct c8-planar B-fragment loads ---------
// B-frag (16 px, chunk c8=ks*4+g) = 256 B contiguous in c8-planar layout ->
// per-lane global_load_dwordx4, no staging, no barriers. A from L2 (L1-reused
// across the och-pair waves). Output written c8-planar (full-sector runs).
template <int MODE>
__global__ __launch_bounds__(256, 4) void conv_direct(
    const unsigned short* __restrict__ Wh,
    const unsigned short* __restrict__ B_, const float* __restrict__ bias,
    const unsigned short* __restrict__ attn, unsigned short* __restrict__ O_) {
  int t = threadIdx.x, wv = t >> 6, lane = t & 63;
  int col = lane & 15, g = lane >> 4;
  int och = wv >> 1, xq = wv & 1;
  int bid = blockIdx.x;
  int g8 = (bid & 7) * 256 + (bid >> 3);   // XCD-chunked
  int xh = g8 & 1;
  int ry = g8 >> 1;
  int b = ry >> 8, y = ry & 255;
  int x0 = xh * 128 + xq * 64;

  // clamped (reflect) input x per (nf, dx)
  int xc[4][3];
#pragma unroll
  for (int nf = 0; nf < 4; ++nf)
#pragma unroll
    for (int dx = 0; dx < 3; ++dx) {
      int xx = x0 + nf * 16 + col + dx - 1;
      xc[nf][dx] = xx < 0 ? 1 : (xx > 255 ? 254 : xx);
    }

  f32x4 acc[3][4];
#pragma unroll
  for (int m = 0; m < 3; ++m)
#pragma unroll
    for (int n = 0; n < 4; ++n) acc[m][n] = (f32x4)0.f;

  size_t bb = (size_t)b * kHW;
#pragma unroll
  for (int dy = 0; dy < 3; ++dy) {
    int yy = y + dy - 1;
    yy = yy < 0 ? 1 : (yy > 255 ? 254 : yy);
    size_t rowp = bb + (size_t)yy * 256;
#pragma unroll
    for (int dx = 0; dx < 3; ++dx) {
      const char* ah = (const char*)Wh +
          ((size_t)(dy * 3 + dx) * 9216 + och * 4608 + col * 96 + g * 8) * 2;
#pragma unroll
      for (int ks = 0; ks < 3; ++ks) {
        short8 Ah[3], Bf[4];
#pragma unroll
        for (int mf = 0; mf < 3; ++mf)
          Ah[mf] = *(const short8*)(ah + (size_t)(mf * 16 * 96 + ks * 32) * 2);
        size_t plane = (size_t)(ks * 4 + g) * kP;
#pragma unroll
        for (int nf = 0; nf < 4; ++nf)
          Bf[nf] = *(const short8*)(B_ + (plane + rowp + xc[nf][dx]) * 8);
#pragma unroll
        for (int mf = 0; mf < 3; ++mf)
#pragma unroll
          for (int nf = 0; nf < 4; ++nf)
            acc[mf][nf] = __builtin_amdgcn_mfma_f32_16x16x32_bf16(Ah[mf], Bf[nf], acc[mf][nf], 0, 0, 0);
      }
    }
  }

  // epilogue: direct c8-planar stores (no LDS)
  size_t prow = bb + (size_t)y * 256;
#pragma unroll
  for (int mf = 0; mf < 3; ++mf) {
    int oc0 = och * 48 + mf * 16 + g * 4;
    int c8o = och * 6 + mf * 2 + (g >> 1);
    f32x4 bv;
#pragma unroll
    for (int r = 0; r < 4; ++r) bv[r] = bias[oc0 + r];
#pragma unroll
    for (int nf = 0; nf < 4; ++nf) {
      size_t p = prow + x0 + nf * 16 + col;
      f32x4 v = acc[mf][nf] + bv;
      if (MODE == 0) {
#pragma unroll
        for (int r = 0; r < 4; ++r) v[r] = fmaxf(v[r], 0.f);
      } else {
        us4 a4 = *(const us4*)(attn + ((size_t)c8o * kP + p) * 8 + (g & 1) * 4);
#pragma unroll
        for (int r = 0; r < 4; ++r) v[r] += bf2f(a4[r]);
      }
      us4 o;
#pragma unroll
      for (int r = 0; r < 4; ++r) o[r] = f2bf(v[r]);
      *(us4*)(O_ + ((size_t)c8o * kP + p) * 8 + (g & 1) * 4) = o;
    }
  }
}

// ---------------- final projection: c8-planar in -> d_out NCHW fp32 ---------
__global__ __launch_bounds__(256, 2) void proj_gemm(
    const unsigned short* __restrict__ Wph, const unsigned short* __restrict__ Wpl,
    const unsigned short* __restrict__ S_, const float* __restrict__ bias,
    float* __restrict__ out) {
  int t = threadIdx.x, wv = t >> 6, lane = t & 63;
  size_t px0 = (size_t)blockIdx.x * 256 + wv * 64;
  int col = lane & 15, g = lane >> 4;
  f32x4 acc[6][4];
#pragma unroll
  for (int m = 0; m < 6; ++m)
#pragma unroll
    for (int n = 0; n < 4; ++n) acc[m][n] = (f32x4)0.f;
  const char* aH = (const char*)Wph + (size_t)(col * 96 + g * 8) * 2;
  const char* aL = (const char*)Wpl + (size_t)(col * 96 + g * 8) * 2;
#pragma unroll
  for (int ks = 0; ks < 3; ++ks) {
    short8 Ah[6], Al[6], Bf[4];
#pragma unroll
    for (int mf = 0; mf < 6; ++mf) {
      Ah[mf] = *(const short8*)(aH + (size_t)(mf * 16 * 96 + ks * 32) * 2);
      Al[mf] = *(const short8*)(aL + (size_t)(mf * 16 * 96 + ks * 32) * 2);
    }
    size_t plane = (size_t)(ks * 4 + g) * kP;
#pragma unroll
    for (int nf = 0; nf < 4; ++nf)
      Bf[nf] = *(const short8*)(S_ + (plane + px0 + nf * 16 + col) * 8);
#pragma unroll
    for (int mf = 0; mf < 6; ++mf)
#pragma unroll
      for (int nf = 0; nf < 4; ++nf) {
        acc[mf][nf] = __builtin_amdgcn_mfma_f32_16x16x32_bf16(Ah[mf], Bf[nf], acc[mf][nf], 0, 0, 0);
        acc[mf][nf] = __builtin_amdgcn_mfma_f32_16x16x32_bf16(Al[mf], Bf[nf], acc[mf][nf], 0, 0, 0);
      }
  }
#pragma unroll
  for (int mf = 0; mf < 6; ++mf) {
    int oc0 = mf * 16 + g * 4;
#pragma unroll
    for (int nf = 0; nf < 4; ++nf) {
      size_t p = px0 + nf * 16 + col;
      size_t bb = p >> 16, pix = p & 65535;
      f32x4 v = acc[mf][nf];
#pragma unroll
      for (int r = 0; r < 4; ++r)
        out[(bb * 96 + oc0 + r) * (size_t)kHW + pix] = v[r] + bias[oc0 + r];
    }
  }
}

extern "C" void kernel_launch(void* const* d_in, const int* in_sizes, int n_in,
                              void* d_out, int out_size, void* d_ws, size_t ws_size,
                              hipStream_t stream) {
  const float* X       = (const float*)d_in[0];
  const float* V_w     = (const float*)d_in[1];
  const float* V_b     = (const float*)d_in[2];
  const float* QK_w    = (const float*)d_in[3];
  const float* QK_b    = (const float*)d_in[4];
  const float* meta_w1 = (const float*)d_in[5];
  const float* meta_b1 = (const float*)d_in[6];
  const float* meta_w2 = (const float*)d_in[7];
  const float* meta_b2 = (const float*)d_in[8];
  const float* conv1_w = (const float*)d_in[9];
  const float* conv1_b = (const float*)d_in[10];
  const float* conv2_w = (const float*)d_in[11];
  const float* conv2_b = (const float*)d_in[12];
  const float* proj_w  = (const float*)d_in[13];
  const float* proj_b  = (const float*)d_in[14];
  float* out = (float*)d_out;

  char* w = (char*)d_ws;
  const size_t PLANE = (size_t)kP * 96 * 2;      // 50,331,648 B
  unsigned short* Xh = (unsigned short*)(w + 0 * PLANE);
  unsigned short* Qp = (unsigned short*)(w + 1 * PLANE);
  unsigned short* Kp = (unsigned short*)(w + 2 * PLANE);
  unsigned short* Vp = (unsigned short*)(w + 3 * PLANE);
  float* bias_tab    = (float*)(w + 4 * PLANE);
  unsigned short* Wqh = (unsigned short*)(w + 4 * PLANE + 98304);
  unsigned short* Wql = Wqh + 27648;
  unsigned short* W1h = Wql + 27648;
  unsigned short* W2h = W1h + 82944;
  unsigned short* Wph = W2h + 82944;
  unsigned short* Wpl = Wph + 9216;
  // stream-ordered aliases (all activation buffers c8-planar)
  unsigned short* T1c = Xh;            // X dead after qkv_gemm
  unsigned short* S2c = Qp;            // Q dead after attn
  unsigned short* attnB = (unsigned short*)out;  // d_out as bf16 c8-planar scratch

  bias_kernel<<<dim3(64), dim3(64), 0, stream>>>(meta_w1, meta_b1, meta_w2, meta_b2, bias_tab);
  prep_weights<<<dim3(324), dim3(256), 0, stream>>>(QK_w, V_w, conv1_w, conv2_w, proj_w,
                                                    Wqh, Wql, W1h, W2h, Wph, Wpl);
  split_x<<<dim3(4096), dim3(256), 0, stream>>>(X, Xh);
  qkv_gemm<<<dim3(1024), dim3(256), 0, stream>>>(Wqh, Wql, Xh, QK_b, V_b, Qp, Kp, Vp);
  attn_mfma<<<dim3(1024, 6), dim3(256), 0, stream>>>(Qp, Kp, Vp, bias_tab, attnB);
  conv_direct<0><<<dim3(2048), dim3(256), 0, stream>>>(W1h, Vp, conv1_b, nullptr, T1c);
  conv_direct<1><<<dim3(2048), dim3(256), 0, stream>>>(W2h, T1c, conv2_b, attnB, S2c);
  proj_gemm<<<dim3(1024), dim3(256), 0, stream>>>(Wph, Wpl, S2c, proj_b, out);
}